// Round 1
// 222.237 us; speedup vs baseline: 1.0245x; 1.0245x over previous
//
#include <hip/hip_runtime.h>

// AttentionLoss: out = sum_{valid}(guide * pred) / sum(tl*ml)
// guide = 1 - exp(-12.5*(n/tl - t/ml)^2);  valid: t < ml[b] && n < tl[b]
// pred [B=64, MEL=2000, TEXT=256] f32; lengths int32 [64].
//
// R1: one batch per block-group, one wave per row via float4, uniform trip.
// R2 (this round):
//   - guide via exp2 with pre-scaled coords: exp(-12.5 d^2) = exp2(-(s*d)^2),
//     s = sqrt(12.5*log2(e)); the negate rides the v_exp_f32 input modifier.
//   - explicit .x/.y/.z/.w (no (&v.x)[e] address-taken pattern), zero-init v,
//     mask-on-load then pure fmaf accumulation.
//   - unroll-2 on the row loop for load ILP.
//   - attn_final: float4 partial loads + wave-parallel "active" reduction.

#define BB 64
#define MEL_MAX 2000
#define TEXT_MAX 256
#define BLK_PER_B 32
#define NBLOCKS (BB * BLK_PER_B)   // 2048

// sqrt(12.5 * log2(e)) = sqrt(18.033688011112043)
#define SCALE 4.2466090f

__global__ __launch_bounds__(256) void attn_partial(
    const float* __restrict__ pred,
    const int* __restrict__ text_len,
    const int* __restrict__ mel_len,
    float* __restrict__ partials)
{
    const int b    = blockIdx.x >> 5;        // 0..63
    const int j    = blockIdx.x & 31;        // 0..31
    const int wave = threadIdx.x >> 6;       // 0..3
    const int lane = threadIdx.x & 63;       // 0..63

    const int mlb = mel_len[b];
    const int tlb = text_len[b];
    const float inv_tl = 1.0f / (float)tlb;
    const float sm     = SCALE / (float)mlb;  // per-row scale for t

    const int n0 = lane << 2;                 // first of 4 text positions
    const bool l0 = (n0     < tlb);
    const bool l1 = (n0 + 1 < tlb);
    const bool l2 = (n0 + 2 < tlb);
    const bool l3 = (n0 + 3 < tlb);

    // pre-scaled text coordinates (hoisted; 4 VGPRs)
    const float nb0 = (float)(n0    ) * inv_tl * SCALE;
    const float nb1 = (float)(n0 + 1) * inv_tl * SCALE;
    const float nb2 = (float)(n0 + 2) * inv_tl * SCALE;
    const float nb3 = (float)(n0 + 3) * inv_tl * SCALE;

    const float* bbase = pred + (size_t)b * (MEL_MAX * TEXT_MAX);

    float acc = 0.0f;
    // rows t = j*4 + wave + 128*k, wave-uniform trip count
    #pragma unroll 2
    for (int t = (j << 2) + wave; t < mlb; t += BLK_PER_B * 4) {
        float4 v = make_float4(0.0f, 0.0f, 0.0f, 0.0f);
        if (l0)
            v = *(const float4*)(bbase + (size_t)t * TEXT_MAX + n0);
        // mask boundary elements once; then the math is a pure fma chain
        const float px = v.x;                  // l0 implied by the load guard
        const float py = l1 ? v.y : 0.0f;
        const float pz = l2 ? v.z : 0.0f;
        const float pw = l3 ? v.w : 0.0f;

        const float tn = (float)t * sm;        // pre-scaled mel coordinate
        float d, g;
        d = nb0 - tn; g = 1.0f - __builtin_amdgcn_exp2f(-(d * d)); acc = fmaf(g, px, acc);
        d = nb1 - tn; g = 1.0f - __builtin_amdgcn_exp2f(-(d * d)); acc = fmaf(g, py, acc);
        d = nb2 - tn; g = 1.0f - __builtin_amdgcn_exp2f(-(d * d)); acc = fmaf(g, pz, acc);
        d = nb3 - tn; g = 1.0f - __builtin_amdgcn_exp2f(-(d * d)); acc = fmaf(g, pw, acc);
    }

    // block reduction: wave64 shuffle then LDS across 4 waves
    for (int off = 32; off > 0; off >>= 1)
        acc += __shfl_down(acc, off, 64);
    __shared__ float s[4];
    if (lane == 0) s[wave] = acc;
    __syncthreads();
    if (threadIdx.x == 0)
        partials[blockIdx.x] = s[0] + s[1] + s[2] + s[3];
}

__global__ __launch_bounds__(256) void attn_final(
    const float* __restrict__ partials,
    const int* __restrict__ text_len,
    const int* __restrict__ mel_len,
    float* __restrict__ out)
{
    const int tid  = threadIdx.x;
    const int wid  = tid >> 6;
    const int lane = tid & 63;

    // 2048 partials = 512 float4 = 256 threads x 2
    const float4* p4 = (const float4*)partials;
    const float4 a = p4[tid];
    const float4 c = p4[tid + 256];
    float acc = (a.x + a.y) + (a.z + a.w) + (c.x + c.y) + (c.z + c.w);
    for (int off = 32; off > 0; off >>= 1)
        acc += __shfl_down(acc, off, 64);

    __shared__ float s[4];
    __shared__ float sact;
    if (lane == 0) s[wid] = acc;
    if (wid == 0) {
        // BB == 64: one batch per lane of wave 0
        float act = (lane < BB) ? (float)text_len[lane] * (float)mel_len[lane] : 0.0f;
        for (int off = 32; off > 0; off >>= 1)
            act += __shfl_down(act, off, 64);
        if (lane == 0) sact = act;
    }
    __syncthreads();
    if (tid == 0)
        out[0] = (s[0] + s[1] + s[2] + s[3]) / sact;  // ATTN_WEIGHT = 1.0
}

extern "C" void kernel_launch(void* const* d_in, const int* in_sizes, int n_in,
                              void* d_out, int out_size, void* d_ws, size_t ws_size,
                              hipStream_t stream)
{
    // inputs: 0 = targets (unused zeros), 1 = predictions, 2 = text_lengths, 3 = mel_lengths
    const float* pred = (const float*)d_in[1];
    const int* tl = (const int*)d_in[2];
    const int* ml = (const int*)d_in[3];
    float* out = (float*)d_out;
    float* partials = (float*)d_ws;   // NBLOCKS floats

    attn_partial<<<NBLOCKS, 256, 0, stream>>>(pred, tl, ml, partials);
    attn_final<<<1, 256, 0, stream>>>(partials, tl, ml, out);
}